// Round 1
// baseline (175.344 us; speedup 1.0000x reference)
//
#include <hip/hip_runtime.h>

#define D 64

typedef float f32x4 __attribute__((ext_vector_type(4)));

// Kernel 1: it_norm[b][t] = item_emb[iids[b]][t] / max(||row||, 1e-12)
__global__ void norm_items_kernel(const float* __restrict__ item_emb,
                                  const int* __restrict__ iids,
                                  float* __restrict__ it_norm) {
    const int b = blockIdx.x;
    const int t = threadIdx.x;       // 0..63, one wave per row
    const int row = iids[b];
    const float x = item_emb[(size_t)row * D + t];
    float ss = x * x;
    #pragma unroll
    for (int off = 32; off > 0; off >>= 1)
        ss += __shfl_xor(ss, off, 64);
    const float n = sqrtf(ss);
    it_norm[(size_t)b * D + t] = x / fmaxf(n, 1e-12f);
}

__device__ __forceinline__ float frcp(float x)  { return __builtin_amdgcn_rcpf(x); }
__device__ __forceinline__ float fsq(float x)   { return __builtin_amdgcn_sqrtf(x); }
__device__ __forceinline__ float frsq(float x)  { return __builtin_amdgcn_rsqf(x); }

// Kernel 2: 4 consecutive u per thread, float4 stores THROUGH L2 (no nt).
// Theory: plain stores let the 32MB L2 write-combine the 14 interleaved
// streams into row-local bursts (the harness fill kernel sustains 6.7 TB/s
// this way); nt stores bypass L2 and were capping us at ~4.5 TB/s.
__global__ __launch_bounds__(256) void diffusion_main_kernel(
        const float* __restrict__ user_emb,
        const float* __restrict__ it_norm,
        const int* __restrict__ inter,
        const float* __restrict__ base_betas,
        float* __restrict__ out,
        int U, int B, int S) {
    const int slot = blockIdx.x * blockDim.x + threadIdx.x;
    const int u0 = slot * 4;
    if (u0 >= U) return;
    const int b = blockIdx.y;
    const bool full = (u0 + 4 <= U);

    // ---- scores for 4 users ----
    float dt[4]  = {0.f, 0.f, 0.f, 0.f};
    float ssq[4] = {0.f, 0.f, 0.f, 0.f};
    const float4* __restrict__ ip = (const float4*)(it_norm + (size_t)b * D);
    #pragma unroll
    for (int k = 0; k < D / 4; ++k) {
        const float4 iv = ip[k];
        #pragma unroll
        for (int c = 0; c < 4; ++c) {
            const int uc = (u0 + c < U) ? (u0 + c) : (U - 1);
            const float4 uv = ((const float4*)(user_emb + (size_t)uc * D))[k];
            dt[c]  += uv.x * iv.x + uv.y * iv.y + uv.z * iv.z + uv.w * iv.w;
            ssq[c] += uv.x * uv.x + uv.y * uv.y + uv.z * uv.z + uv.w * uv.w;
        }
    }

    const size_t BU  = (size_t)B * U;
    const size_t gid = (size_t)b * U + u0;

    int itv[4];
    if (full) {
        const int4 i4 = *(const int4*)(inter + gid);
        itv[0] = i4.x; itv[1] = i4.y; itv[2] = i4.z; itv[3] = i4.w;
    } else {
        #pragma unroll
        for (int c = 0; c < 4; ++c)
            itv[c] = (u0 + c < U) ? inter[gid + c] : 1;
    }

    float g[4];
    #pragma unroll
    for (int c = 0; c < 4; ++c) {
        float score = dt[c] * frcp(fmaxf(fsq(ssq[c]), 1e-12f));
        score = fminf(fmaxf(score, -1.0f), 1.0f);
        if (itv[c] != 1) score = -score;
        g[c] = 1.0f - 0.01f * __expf(3.0f * score);
    }

    const size_t SBU = (size_t)S * BU;
    float* __restrict__ o = out + gid;

    // carried state
    float acp[4]   = {1.f, 1.f, 1.f, 1.f};
    float om_p[4]  = {0.f, 0.f, 0.f, 0.f};   // 1 - acp_prev
    float sap_p[4] = {1.f, 1.f, 1.f, 1.f};   // sqrt(acp_prev)
    float som_p[4] = {0.f, 0.f, 0.f, 0.f};   // sqrt(1 - acp_prev)

    for (int s = 0; s < S; ++s) {
        const float bb = base_betas[s];
        float beta[4], aprev[4], anew[4], om[4], rc[4], so[4], sa[4],
              rsa[4], srA[4], sqA[4], lom[4], f2a[4];
        #pragma unroll
        for (int c = 0; c < 4; ++c) {
            const float bt = g[c] * bb;
            const float al = 1.0f - bt;
            aprev[c] = acp[c];
            const float a = acp[c] * al;
            acp[c] = a;  anew[c] = a;
            const float omc = 1.0f - a;
            beta[c] = bt;       om[c]  = omc;
            rc[c]   = frcp(omc);
            so[c]   = fsq(omc);
            sa[c]   = fsq(a);
            rsa[c]  = frsq(a);
            srA[c]  = frsq(al);           // sqrt(1/alpha)
            sqA[c]  = al * srA[c];        // sqrt(alpha)
            lom[c]  = __logf(omc);
            f2a[c]  = som_p[c] * frcp(so[c]);
        }
        const size_t soff = (size_t)s * BU;

        #define STV(k, e0, e1, e2, e3, extra)                                   \
            do {                                                                \
                f32x4 _v = {(e0), (e1), (e2), (e3)};                            \
                float* _p = o + (size_t)(k) * SBU + soff + (extra);             \
                if (full) *(f32x4*)_p = _v;                                     \
                else {                                                          \
                    for (int _c = 0; _c < 4; ++_c)                              \
                        if (u0 + _c < U) _p[_c] = _v[_c];                       \
                }                                                               \
            } while (0)
        #define ST4(k, arr) STV(k, arr[0], arr[1], arr[2], arr[3], 0)

        ST4(0, srA);                                   // sqrt_recip_alphas
        ST4(1, anew);                                  // alphas_cumprod
        ST4(2, so);                                    // sqrt_one_minus_acp
        ST4(3, aprev);                                 // acp_prev
        if (s > 0)
            STV(4, anew[0], anew[1], anew[2], anew[3], -(ptrdiff_t)BU); // acp_next[s-1]
        ST4(5, sa);                                    // sqrt_acp
        ST4(6, lom);                                   // log_one_minus_acp
        ST4(7, rsa);                                   // sqrt_recip_acp
        STV(8, so[0]*rsa[0], so[1]*rsa[1], so[2]*rsa[2], so[3]*rsa[3], 0);  // sqrt_recipm1_acp
        STV(9, beta[0]*sap_p[0]*rc[0], beta[1]*sap_p[1]*rc[1],
               beta[2]*sap_p[2]*rc[2], beta[3]*sap_p[3]*rc[3], 0);          // posterior_mean_coef1
        STV(10, om_p[0]*sqA[0]*rc[0], om_p[1]*sqA[1]*rc[1],
                om_p[2]*sqA[2]*rc[2], om_p[3]*sqA[3]*rc[3], 0);             // posterior_mean_coef2
        ST4(11, f2a);                                  // fast_posterior_coef2
        STV(12, sa[0]*f2a[0], sa[1]*f2a[1], sa[2]*f2a[2], sa[3]*f2a[3], 0); // fast_posterior_coef3
        STV(13, beta[0]*om_p[0]*rc[0], beta[1]*om_p[1]*rc[1],
                beta[2]*om_p[2]*rc[2], beta[3]*om_p[3]*rc[3], 0);           // posterior_variance

        // update carries (after all uses)
        #pragma unroll
        for (int c = 0; c < 4; ++c) {
            om_p[c]  = om[c];
            sap_p[c] = sa[c];
            som_p[c] = so[c];
        }
        #undef ST4
        #undef STV
    }
    // acp_next[S-1] = 0
    {
        float* _p = o + 4 * SBU + (size_t)(S - 1) * BU;
        if (full) {
            f32x4 _z = {0.f, 0.f, 0.f, 0.f};
            *(f32x4*)_p = _z;
        } else {
            for (int _c = 0; _c < 4; ++_c)
                if (u0 + _c < U) _p[_c] = 0.f;
        }
    }
}

extern "C" void kernel_launch(void* const* d_in, const int* in_sizes, int n_in,
                              void* d_out, int out_size, void* d_ws, size_t ws_size,
                              hipStream_t stream) {
    const float* user_emb   = (const float*)d_in[0];   // [U, 64]
    const float* item_emb   = (const float*)d_in[1];   // [I, 64]
    const int*   iids       = (const int*)d_in[2];     // [B]
    const int*   inter      = (const int*)d_in[3];     // [B, U]
    const float* base_betas = (const float*)d_in[4];   // [S]

    const int U = in_sizes[0] / D;
    const int B = in_sizes[2];
    const int S = in_sizes[4];

    float* it_norm = (float*)d_ws;                     // [B, 64] = 32 KB
    float* out     = (float*)d_out;

    norm_items_kernel<<<B, 64, 0, stream>>>(item_emb, iids, it_norm);

    const int slots = (U + 3) / 4;
    dim3 grid((slots + 255) / 256, B);
    diffusion_main_kernel<<<grid, 256, 0, stream>>>(user_emb, it_norm, inter,
                                                    base_betas, out, U, B, S);
}